// Round 15
// baseline (277.173 us; speedup 1.0000x reference)
//
#include <hip/hip_runtime.h>

// ScaledAttention B=8,T=2048,D=1024 single-head, SCALE=1/8.
// cvt -> QKV proj -> causal QK^T (raw f16 S) -> softmax (applies causal mask)
// -> PV. Unified core: 128x128 tile, 256 thr (4 waves 2Mx2N, acc[4][4]->AGPR),
// A+B staged via global_load_lds into a 2x32KB DOUBLE buffer, counted
// vmcnt(8) (never 0 mid-loop), chunk^=(row&7) swizzle both sides.
// 64KB LDS + ~150 regs -> 2 blocks/CU (TLP) x 1-tile-deep prefetch (ILP).

typedef float f32x4 __attribute__((ext_vector_type(4)));
typedef _Float16 half8 __attribute__((ext_vector_type(8)));
typedef _Float16 half4 __attribute__((ext_vector_type(4)));

#define DEVINL __device__ __forceinline__
static constexpr float ATT_SCALE = 0.125f;  // 1/sqrt(1024/16)

DEVINL void gload_lds16(const _Float16* g, _Float16* l) {
  __builtin_amdgcn_global_load_lds((const __attribute__((address_space(1))) void*)g,
                                   (__attribute__((address_space(3))) void*)l, 16, 0, 0);
}

#define SBAR() __builtin_amdgcn_sched_barrier(0)

// LDS (f16 units): buf b @ b*16384: A[128 rows][64 k] @+0, B[128][64] @+8192.
// Element (r, 16B-chunk c) at phys chunk c ^ (r&7); rows are 128B = 8 chunks.
// Loop t: read 16 frags buf(t) | lgkm0 | bar1 | STG(t+2)->buf(t) | vmcnt(8)
// [t+1 landed, t+2 in flight] | bar2 | 32 MFMA.
template <int LDA, int LDB, class GA, class GB>
DEVINL void core128(GA ga, GB gb, int NT, _Float16* lds, int tid, f32x4 acc[4][4]) {
  const int l = tid & 63, w = tid >> 6;
  const int wm = w >> 1, wn = w & 1;
  const int lr = l & 15, lk = l >> 4;
  int srow[4], scol[4];
#pragma unroll
  for (int i = 0; i < 4; ++i) {
    const int P = i * 256 + tid;
    srow[i] = P >> 3;
    scol[i] = (P & 7) ^ (srow[i] & 7);
  }
  int aoff[4], boff[4];
#pragma unroll
  for (int i = 0; i < 4; ++i) {
    const int ra = wm * 64 + i * 16 + lr;
    aoff[i] = ra * 128 + ((lk ^ (ra & 7)) << 4);
    const int rb = wn * 64 + i * 16 + lr;
    boff[i] = 16384 + rb * 128 + ((lk ^ (rb & 7)) << 4);
  }
  auto STG = [&](int t) {
    const _Float16* gA = ga(t);
    const _Float16* gB = gb(t);
    _Float16* dst = lds + (t & 1) * 16384;
#pragma unroll
    for (int i = 0; i < 4; ++i)
      gload_lds16(gA + (size_t)srow[i] * LDA + scol[i] * 8,
                  dst + i * 2048 + w * 512);
#pragma unroll
    for (int i = 0; i < 4; ++i)
      gload_lds16(gB + (size_t)srow[i] * LDB + scol[i] * 8,
                  dst + 8192 + i * 2048 + w * 512);
  };

  half8 a[4][2], b[4][2];
  STG(0);
  if (NT > 1) STG(1);
  asm volatile("s_waitcnt vmcnt(8)" ::: "memory");  // tile0 landed (8 newest may fly)
  __builtin_amdgcn_s_barrier();

  for (int t = 0; t < NT; ++t) {
    const char* L = (const char*)(lds + (t & 1) * 16384);
#pragma unroll
    for (int i = 0; i < 4; ++i) {
      a[i][0] = *(const half8*)(L + aoff[i]);
      a[i][1] = *(const half8*)(L + (aoff[i] ^ 64));
      b[i][0] = *(const half8*)(L + (boff[i] - 16384) + 16384);
      b[i][1] = *(const half8*)(L + ((boff[i] - 16384) ^ 64) + 16384);
    }
    asm volatile("s_waitcnt lgkmcnt(0)" ::: "memory");
    SBAR();
    __builtin_amdgcn_s_barrier();      // bar1: all waves done reading buf(t)
    if (t + 2 < NT) {
      STG(t + 2);                      // overwrite buf(t) (reads drained)
      asm volatile("s_waitcnt vmcnt(8)" ::: "memory");  // t+1 landed
    } else {
      asm volatile("s_waitcnt vmcnt(0)" ::: "memory");  // tail: drain all
    }
    SBAR();
    __builtin_amdgcn_s_barrier();      // bar2: t+1 landed for ALL waves
    __builtin_amdgcn_s_setprio(1);
#pragma unroll
    for (int kk = 0; kk < 2; ++kk)
#pragma unroll
      for (int i = 0; i < 4; ++i)
#pragma unroll
        for (int j = 0; j < 4; ++j)
          acc[i][j] = __builtin_amdgcn_mfma_f32_16x16x32_f16(a[i][kk], b[j][kk], acc[i][j], 0, 0, 0);
    __builtin_amdgcn_s_setprio(0);
    SBAR();
  }
}

// ---------------------------------------------------------------------------
__global__ __launch_bounds__(256) void cvt_all(const float* __restrict__ x,
                                               const float* __restrict__ wq,
                                               const float* __restrict__ wk,
                                               const float* __restrict__ wv,
                                               _Float16* __restrict__ xh,
                                               _Float16* __restrict__ wqh,
                                               _Float16* __restrict__ wkh,
                                               _Float16* __restrict__ wvh) {
  const int n8 = 2490368;
  for (int i = blockIdx.x * 256 + threadIdx.x; i < n8; i += 2048 * 256) {
    const float* src; _Float16* dst; int off;
    if (i < 2097152)      { src = x;  dst = xh;  off = i; }
    else if (i < 2228224) { src = wq; dst = wqh; off = i - 2097152; }
    else if (i < 2359296) { src = wk; dst = wkh; off = i - 2228224; }
    else                  { src = wv; dst = wvh; off = i - 2359296; }
    const float4* p = (const float4*)src + (size_t)off * 2;
    float4 v0 = p[0], v1 = p[1];
    half8 h;
    h[0] = (_Float16)v0.x; h[1] = (_Float16)v0.y; h[2] = (_Float16)v0.z; h[3] = (_Float16)v0.w;
    h[4] = (_Float16)v1.x; h[5] = (_Float16)v1.y; h[6] = (_Float16)v1.z; h[7] = (_Float16)v1.w;
    *((half8*)dst + off) = h;
  }
}

// Fused QKV: C[m,n]=sum_k x[m,k]W[n,k]+b[n]. 3072 jobs of 128x128.
__global__ __launch_bounds__(256, 2) void gemm_qkv(
    const _Float16* __restrict__ xh, const _Float16* __restrict__ Wqh,
    const _Float16* __restrict__ Wkh, const _Float16* __restrict__ Wvh,
    const float* __restrict__ bq, const float* __restrict__ bk,
    const float* __restrict__ bv, _Float16* __restrict__ Qh,
    _Float16* __restrict__ Kh, _Float16* __restrict__ VT) {
  __shared__ _Float16 lds[32768];  // 64KB: 2 x (A+B) bufs; reused by epilogue
  const int tid = threadIdx.x;
  const int bid = blockIdx.x;
  const int swz = (bid & 7) * 384 + (bid >> 3);  // XCD swizzle, 3072%8==0
  const int mt = swz / 24, nt = swz % 24;
  const int sel = nt >> 3;
  const _Float16* Wsel = sel == 0 ? Wqh : (sel == 1 ? Wkh : Wvh);
  const float* bsel = sel == 0 ? bq : (sel == 1 ? bk : bv);
  const int n0 = (nt & 7) * 128;
  const _Float16* Ab = xh + (size_t)mt * 128 * 1024;
  const _Float16* Bb = Wsel + (size_t)n0 * 1024;
  f32x4 acc[4][4] = {};
  auto ga = [&](int t) { return Ab + t * 64; };
  auto gb = [&](int t) { return Bb + t * 64; };
  core128<1024, 1024>(ga, gb, 16, lds, tid, acc);
  const int l = tid & 63, w = tid >> 6;
  const int wm = w >> 1, wn = w & 1;
  const int lr = l & 15, lk = l >> 4;
  __syncthreads();
#pragma unroll
  for (int i = 0; i < 4; ++i) {
#pragma unroll
    for (int j = 0; j < 4; ++j) {
      const int col = wn * 64 + j * 16 + lr;
      const float bvv = bsel[n0 + col];
#pragma unroll
      for (int r = 0; r < 4; ++r) {
        const int row = wm * 64 + i * 16 + lk * 4 + r;
        const float v = acc[i][j][r] + bvv;
        if (sel < 2)
          lds[row * 128 + ((col + (row >> 2) * 8) & 127)] = (_Float16)v;
        else  // transposed: [d=col][t=row]
          lds[col * 128 + ((row + (col >> 2) * 8) & 127)] = (_Float16)v;
      }
    }
  }
  __syncthreads();
#pragma unroll
  for (int i = 0; i < 8; ++i) {
    const int c = i * 256 + tid;
    const int row = c >> 4, c8 = c & 15;
    half8 v = *(const half8*)&lds[row * 128 + ((c8 * 8 + (row >> 2) * 8) & 127)];
    if (sel < 2) {
      _Float16* Out = sel == 0 ? Qh : Kh;
      *(half8*)&Out[(size_t)(mt * 128 + row) * 1024 + n0 + c8 * 8] = v;
    } else {
      const int bb = mt >> 4, t0 = (mt & 15) * 128;
      *(half8*)&VT[((size_t)bb * 1024 + n0 + row) * 2048 + t0 + c8 * 8] = v;
    }
  }
}

// Causal QK^T: 1088 jobs (b, qt2, jn2<=qt2) of 128x128 -> raw scaled f16 S in
// compact tri layout [b][tri36(256-tiles)][256][256]. Mask applied in softmax.
__global__ __launch_bounds__(256, 2) void gemm_qk(const _Float16* __restrict__ Qh,
                                                  const _Float16* __restrict__ Kh,
                                                  _Float16* __restrict__ Sc) {
  __shared__ _Float16 lds[32768];
  const int tid = threadIdx.x;
  const int bid = blockIdx.x;
  const int b = bid / 136, r = bid % 136;
  int qt2 = 0, cum = 0;
  while (cum + qt2 + 1 <= r) { cum += qt2 + 1; ++qt2; }
  const int jn2 = r - cum;  // 0..qt2
  const _Float16* Ab = Qh + ((size_t)b * 2048 + qt2 * 128) * 1024;
  const _Float16* Bb = Kh + ((size_t)b * 2048 + jn2 * 128) * 1024;
  f32x4 acc[4][4] = {};
  auto ga = [&](int t) { return Ab + t * 64; };
  auto gb = [&](int t) { return Bb + t * 64; };
  core128<1024, 1024>(ga, gb, 16, lds, tid, acc);
  const int l = tid & 63, w = tid >> 6;
  const int wm = w >> 1, wn = w & 1;
  const int lr = l & 15, lk = l >> 4;
  const int qt = qt2 >> 1;
  _Float16* St = Sc + ((size_t)b * 36 + (size_t)(qt * (qt + 1) / 2) + (jn2 >> 1)) * 65536 +
                 (qt2 & 1) * 32768 + (jn2 & 1) * 128;
#pragma unroll
  for (int i = 0; i < 4; ++i) {
#pragma unroll
    for (int jj = 0; jj < 4; ++jj) {
      const int col = wn * 64 + jj * 16 + lr;
#pragma unroll
      for (int rr = 0; rr < 4; ++rr) {
        const int row = wm * 64 + i * 16 + lk * 4 + rr;
        St[(size_t)row * 256 + col] = (_Float16)(acc[i][jj][rr] * ATT_SCALE);
      }
    }
  }
}

// One wave per row: softmax over f16 compact S row; applies causal mask k<=q
// (S above diagonal may be garbage). Writes f16 P (0 where masked).
__global__ __launch_bounds__(256) void softmax_p(const _Float16* __restrict__ Sc,
                                                 _Float16* __restrict__ Pc) {
  const int l = threadIdx.x & 63;
  const int gid = blockIdx.x * 4 + (threadIdx.x >> 6);
  const int b = gid >> 11, q = gid & 2047;
  const int qt = q >> 8, rq = q & 255;
  const int ntile = qt + 1;
  const size_t base = ((size_t)b * 36 + (size_t)(qt * (qt + 1) / 2)) * 65536 +
                      (size_t)rq * 256 + l * 4;
  float vx[32];
  float m = -__builtin_inff();
#pragma unroll
  for (int c = 0; c < 8; ++c) {
    const int k0 = c * 256 + l * 4;
    float x0 = -__builtin_inff(), x1 = x0, x2 = x0, x3 = x0;
    if (c < ntile) {
      half4 t = *(const half4*)&Sc[base + (size_t)c * 65536];
      x0 = (k0 <= q)     ? (float)t[0] : -__builtin_inff();
      x1 = (k0 + 1 <= q) ? (float)t[1] : -__builtin_inff();
      x2 = (k0 + 2 <= q) ? (float)t[2] : -__builtin_inff();
      x3 = (k0 + 3 <= q) ? (float)t[3] : -__builtin_inff();
    }
    vx[4 * c] = x0; vx[4 * c + 1] = x1; vx[4 * c + 2] = x2; vx[4 * c + 3] = x3;
    m = fmaxf(m, fmaxf(fmaxf(x0, x1), fmaxf(x2, x3)));
  }
#pragma unroll
  for (int s = 1; s < 64; s <<= 1) m = fmaxf(m, __shfl_xor(m, s, 64));
  float sum = 0.f;
#pragma unroll
  for (int i = 0; i < 32; ++i) { vx[i] = __expf(vx[i] - m); sum += vx[i]; }
#pragma unroll
  for (int s = 1; s < 64; s <<= 1) sum += __shfl_xor(sum, s, 64);
  const float inv = 1.f / sum;
  _Float16* Pb = Pc + base;
#pragma unroll
  for (int c = 0; c < 8; ++c) {
    if (c < ntile) {
      half4 p;
      p[0] = (_Float16)(vx[4 * c] * inv);
      p[1] = (_Float16)(vx[4 * c + 1] * inv);
      p[2] = (_Float16)(vx[4 * c + 2] * inv);
      p[3] = (_Float16)(vx[4 * c + 3] * inv);
      *(half4*)&Pb[(size_t)c * 65536] = p;
    }
  }
}

// PV: 1024 jobs (qt2 descending = LPT), each 128(q) x 128(d); NT=(qt2+1)*2.
__global__ __launch_bounds__(256, 2) void gemm_pv(const _Float16* __restrict__ Pc,
                                                  const _Float16* __restrict__ VT,
                                                  float* __restrict__ O) {
  __shared__ _Float16 lds[32768];
  const int tid = threadIdx.x;
  const int bid = blockIdx.x;
  const int qt2 = 15 - (bid >> 6);
  const int dt = (bid >> 3) & 7, b = bid & 7;
  const int qt = qt2 >> 1;
  const size_t triB = (size_t)b * 36 + (size_t)(qt * (qt + 1) / 2);
  const _Float16* Vb = VT + ((size_t)b * 1024 + dt * 128) * 2048;
  f32x4 acc[4][4] = {};
  auto ga = [&](int t) {
    return Pc + (triB + (t >> 2)) * 65536 + (qt2 & 1) * 32768 + (t & 3) * 64;
  };
  auto gb = [&](int t) { return Vb + t * 64; };
  core128<256, 2048>(ga, gb, (qt2 + 1) * 2, lds, tid, acc);
  const int l = tid & 63, w = tid >> 6;
  const int wm = w >> 1, wn = w & 1;
  const int lr = l & 15, lk = l >> 4;
#pragma unroll
  for (int i = 0; i < 4; ++i) {
#pragma unroll
    for (int jj = 0; jj < 4; ++jj) {
      const int cg = dt * 128 + wn * 64 + jj * 16 + lr;
#pragma unroll
      for (int rr = 0; rr < 4; ++rr) {
        const int rg = qt2 * 128 + wm * 64 + i * 16 + lk * 4 + rr;
        O[((size_t)b * 2048 + rg) * 1024 + cg] = acc[i][jj][rr];
      }
    }
  }
}

extern "C" void kernel_launch(void* const* d_in, const int* in_sizes, int n_in,
                              void* d_out, int out_size, void* d_ws, size_t ws_size,
                              hipStream_t stream) {
  const float* x    = (const float*)d_in[0];
  const float* Wq_w = (const float*)d_in[1];
  const float* Wq_b = (const float*)d_in[2];
  const float* Wk_w = (const float*)d_in[3];
  const float* Wk_b = (const float*)d_in[4];
  const float* Wv_w = (const float*)d_in[5];
  const float* Wv_b = (const float*)d_in[6];
  float* out = (float*)d_out;
  char* ws = (char*)d_ws;
  _Float16* xh  = (_Float16*)(ws);              // 32 MiB (dead after proj)
  _Float16* Wqh = (_Float16*)(ws + 33554432);
  _Float16* Wkh = (_Float16*)(ws + 35651584);
  _Float16* Wvh = (_Float16*)(ws + 37748736);
  _Float16* Sc  = (_Float16*)(ws);              // f16 compact tri S (aliases xh+W)
  _Float16* Qh  = (_Float16*)(ws + 75497472);   // 32 MiB
  _Float16* Kh  = (_Float16*)(ws + 109051904);  // 32 MiB
  _Float16* Pc  = (_Float16*)(ws + 75497472);   // f16 compact tri P (aliases Q/K)
  _Float16* VT  = (_Float16*)(ws + 142606336);  // 32 MiB

  cvt_all<<<2048, 256, 0, stream>>>(x, Wq_w, Wk_w, Wv_w, xh, Wqh, Wkh, Wvh);
  gemm_qkv<<<3072, 256, 0, stream>>>(xh, Wqh, Wkh, Wvh, Wq_b, Wk_b, Wv_b, Qh, Kh, VT);
  gemm_qk<<<1088, 256, 0, stream>>>(Qh, Kh, Sc);
  softmax_p<<<4096, 256, 0, stream>>>(Sc, Pc);
  gemm_pv<<<1024, 256, 0, stream>>>(Pc, VT, out);
}

// Round 16
// 244.546 us; speedup vs baseline: 1.1334x; 1.1334x over previous
//
#include <hip/hip_runtime.h>

// ScaledAttention B=8,T=2048,D=1024 single-head, SCALE=1/8.
// cvt -> QKV proj -> causal QK^T (raw f16 S) -> softmax (applies causal mask)
// -> PV. Unified m97-style core (R14): 128x128 tile, 256 thr (4 waves 2Mx2N,
// acc[4][4]->AGPR), A+B staged global_load_lds into ONE 32KB buffer,
// 2-barrier full-drain loop, chunk^=(row&7) swizzle, 3 blocks/CU.
// R16: batch-per-XCD bijective swizzles for qk and pv (L2 panel locality).

typedef float f32x4 __attribute__((ext_vector_type(4)));
typedef _Float16 half8 __attribute__((ext_vector_type(8)));
typedef _Float16 half4 __attribute__((ext_vector_type(4)));

#define DEVINL __device__ __forceinline__
static constexpr float ATT_SCALE = 0.125f;  // 1/sqrt(1024/16)

DEVINL void gload_lds16(const _Float16* g, _Float16* l) {
  __builtin_amdgcn_global_load_lds((const __attribute__((address_space(1))) void*)g,
                                   (__attribute__((address_space(3))) void*)l, 16, 0, 0);
}

#define SBAR() __builtin_amdgcn_sched_barrier(0)

// LDS (f16 units): A[128 rows][64 k] @0 (16KB), B[128][64] @8192 (16KB).
// Element (r, 16B-chunk c) at phys chunk c ^ (r&7); rows are 128B = 8 chunks.
// Loop: read 16 frags | lgkm0 | bar1 | stage(t+1) | vmcnt(0) | bar2 | 32 MFMA.
template <int LDA, int LDB, class GA, class GB>
DEVINL void core128(GA ga, GB gb, int NT, _Float16* lds, int tid, f32x4 acc[4][4]) {
  const int l = tid & 63, w = tid >> 6;
  const int wm = w >> 1, wn = w & 1;
  const int lr = l & 15, lk = l >> 4;
  int srow[4], scol[4];
#pragma unroll
  for (int i = 0; i < 4; ++i) {
    const int P = i * 256 + tid;
    srow[i] = P >> 3;
    scol[i] = (P & 7) ^ (srow[i] & 7);
  }
  int aoff[4], boff[4];
#pragma unroll
  for (int i = 0; i < 4; ++i) {
    const int ra = wm * 64 + i * 16 + lr;
    aoff[i] = ra * 128 + ((lk ^ (ra & 7)) << 4);
    const int rb = wn * 64 + i * 16 + lr;
    boff[i] = 16384 + rb * 128 + ((lk ^ (rb & 7)) << 4);
  }
  auto STG = [&](int t) {
    const _Float16* gA = ga(t);
    const _Float16* gB = gb(t);
#pragma unroll
    for (int i = 0; i < 4; ++i)
      gload_lds16(gA + (size_t)srow[i] * LDA + scol[i] * 8,
                  lds + i * 2048 + w * 512);
#pragma unroll
    for (int i = 0; i < 4; ++i)
      gload_lds16(gB + (size_t)srow[i] * LDB + scol[i] * 8,
                  lds + 8192 + i * 2048 + w * 512);
  };

  half8 a[4][2], b[4][2];
  STG(0);
  asm volatile("s_waitcnt vmcnt(0)" ::: "memory");
  __builtin_amdgcn_s_barrier();

  for (int t = 0; t < NT; ++t) {
    const char* L = (const char*)lds;
#pragma unroll
    for (int i = 0; i < 4; ++i) {
      a[i][0] = *(const half8*)(L + aoff[i]);
      a[i][1] = *(const half8*)(L + (aoff[i] ^ 64));
      b[i][0] = *(const half8*)(L + boff[i]);
      b[i][1] = *(const half8*)(L + (boff[i] ^ 64));
    }
    asm volatile("s_waitcnt lgkmcnt(0)" ::: "memory");
    SBAR();
    __builtin_amdgcn_s_barrier();      // bar1: all waves done reading buffer
    if (t + 1 < NT) STG(t + 1);        // overwrite buffer
    asm volatile("s_waitcnt vmcnt(0)" ::: "memory");
    SBAR();
    __builtin_amdgcn_s_barrier();      // bar2: next tile resident for all
    __builtin_amdgcn_s_setprio(1);
#pragma unroll
    for (int kk = 0; kk < 2; ++kk)
#pragma unroll
      for (int i = 0; i < 4; ++i)
#pragma unroll
        for (int j = 0; j < 4; ++j)
          acc[i][j] = __builtin_amdgcn_mfma_f32_16x16x32_f16(a[i][kk], b[j][kk], acc[i][j], 0, 0, 0);
    __builtin_amdgcn_s_setprio(0);
    SBAR();
  }
}

// ---------------------------------------------------------------------------
__global__ __launch_bounds__(256) void cvt_all(const float* __restrict__ x,
                                               const float* __restrict__ wq,
                                               const float* __restrict__ wk,
                                               const float* __restrict__ wv,
                                               _Float16* __restrict__ xh,
                                               _Float16* __restrict__ wqh,
                                               _Float16* __restrict__ wkh,
                                               _Float16* __restrict__ wvh) {
  const int n8 = 2490368;
  for (int i = blockIdx.x * 256 + threadIdx.x; i < n8; i += 2048 * 256) {
    const float* src; _Float16* dst; int off;
    if (i < 2097152)      { src = x;  dst = xh;  off = i; }
    else if (i < 2228224) { src = wq; dst = wqh; off = i - 2097152; }
    else if (i < 2359296) { src = wk; dst = wkh; off = i - 2228224; }
    else                  { src = wv; dst = wvh; off = i - 2359296; }
    const float4* p = (const float4*)src + (size_t)off * 2;
    float4 v0 = p[0], v1 = p[1];
    half8 h;
    h[0] = (_Float16)v0.x; h[1] = (_Float16)v0.y; h[2] = (_Float16)v0.z; h[3] = (_Float16)v0.w;
    h[4] = (_Float16)v1.x; h[5] = (_Float16)v1.y; h[6] = (_Float16)v1.z; h[7] = (_Float16)v1.w;
    *((half8*)dst + off) = h;
  }
}

// Fused QKV: C[m,n]=sum_k x[m,k]W[n,k]+b[n]. 3072 jobs of 128x128 (4.0 rounds).
__global__ __launch_bounds__(256, 3) void gemm_qkv(
    const _Float16* __restrict__ xh, const _Float16* __restrict__ Wqh,
    const _Float16* __restrict__ Wkh, const _Float16* __restrict__ Wvh,
    const float* __restrict__ bq, const float* __restrict__ bk,
    const float* __restrict__ bv, _Float16* __restrict__ Qh,
    _Float16* __restrict__ Kh, _Float16* __restrict__ VT) {
  __shared__ _Float16 lds[16384];  // 32KB: A+B staging; reused by epilogue
  const int tid = threadIdx.x;
  const int bid = blockIdx.x;
  const int swz = (bid & 7) * 384 + (bid >> 3);  // XCD swizzle, 3072%8==0
  const int mt = swz / 24, nt = swz % 24;
  const int sel = nt >> 3;
  const _Float16* Wsel = sel == 0 ? Wqh : (sel == 1 ? Wkh : Wvh);
  const float* bsel = sel == 0 ? bq : (sel == 1 ? bk : bv);
  const int n0 = (nt & 7) * 128;
  const _Float16* Ab = xh + (size_t)mt * 128 * 1024;
  const _Float16* Bb = Wsel + (size_t)n0 * 1024;
  f32x4 acc[4][4] = {};
  auto ga = [&](int t) { return Ab + t * 64; };
  auto gb = [&](int t) { return Bb + t * 64; };
  core128<1024, 1024>(ga, gb, 16, lds, tid, acc);
  const int l = tid & 63, w = tid >> 6;
  const int wm = w >> 1, wn = w & 1;
  const int lr = l & 15, lk = l >> 4;
  __syncthreads();
#pragma unroll
  for (int i = 0; i < 4; ++i) {
#pragma unroll
    for (int j = 0; j < 4; ++j) {
      const int col = wn * 64 + j * 16 + lr;
      const float bvv = bsel[n0 + col];
#pragma unroll
      for (int r = 0; r < 4; ++r) {
        const int row = wm * 64 + i * 16 + lk * 4 + r;
        const float v = acc[i][j][r] + bvv;
        if (sel < 2)
          lds[row * 128 + ((col + (row >> 2) * 8) & 127)] = (_Float16)v;
        else  // transposed: [d=col][t=row]
          lds[col * 128 + ((row + (col >> 2) * 8) & 127)] = (_Float16)v;
      }
    }
  }
  __syncthreads();
#pragma unroll
  for (int i = 0; i < 8; ++i) {
    const int c = i * 256 + tid;
    const int row = c >> 4, c8 = c & 15;
    half8 v = *(const half8*)&lds[row * 128 + ((c8 * 8 + (row >> 2) * 8) & 127)];
    if (sel < 2) {
      _Float16* Out = sel == 0 ? Qh : Kh;
      *(half8*)&Out[(size_t)(mt * 128 + row) * 1024 + n0 + c8 * 8] = v;
    } else {
      const int bb = mt >> 4, t0 = (mt & 15) * 128;
      *(half8*)&VT[((size_t)bb * 1024 + n0 + row) * 2048 + t0 + c8 * 8] = v;
    }
  }
}

// Causal QK^T: 1088 jobs of 128x128 -> raw scaled f16 S in compact tri layout
// [b][tri36(256-tiles)][256][256]. Mask applied in softmax.
// XCD swizzle: j=(bid&7)*136+(bid>>3); b=j/136 -> one batch per XCD.
__global__ __launch_bounds__(256, 3) void gemm_qk(const _Float16* __restrict__ Qh,
                                                  const _Float16* __restrict__ Kh,
                                                  _Float16* __restrict__ Sc) {
  __shared__ _Float16 lds[16384];
  const int tid = threadIdx.x;
  const int bid = blockIdx.x;
  const int j = (bid & 7) * 136 + (bid >> 3);  // 1088 = 8*136, bijective
  const int b = j / 136, r = j % 136;
  int qt2 = 0, cum = 0;
  while (cum + qt2 + 1 <= r) { cum += qt2 + 1; ++qt2; }
  const int jn2 = r - cum;  // 0..qt2
  const _Float16* Ab = Qh + ((size_t)b * 2048 + qt2 * 128) * 1024;
  const _Float16* Bb = Kh + ((size_t)b * 2048 + jn2 * 128) * 1024;
  f32x4 acc[4][4] = {};
  auto ga = [&](int t) { return Ab + t * 64; };
  auto gb = [&](int t) { return Bb + t * 64; };
  core128<1024, 1024>(ga, gb, 16, lds, tid, acc);
  const int l = tid & 63, w = tid >> 6;
  const int wm = w >> 1, wn = w & 1;
  const int lr = l & 15, lk = l >> 4;
  const int qt = qt2 >> 1;
  _Float16* St = Sc + ((size_t)b * 36 + (size_t)(qt * (qt + 1) / 2) + (jn2 >> 1)) * 65536 +
                 (qt2 & 1) * 32768 + (jn2 & 1) * 128;
#pragma unroll
  for (int i = 0; i < 4; ++i) {
#pragma unroll
    for (int jj = 0; jj < 4; ++jj) {
      const int col = wn * 64 + jj * 16 + lr;
#pragma unroll
      for (int rr = 0; rr < 4; ++rr) {
        const int row = wm * 64 + i * 16 + lk * 4 + rr;
        St[(size_t)row * 256 + col] = (_Float16)(acc[i][jj][rr] * ATT_SCALE);
      }
    }
  }
}

// One wave per row: softmax over f16 compact S row; applies causal mask k<=q
// (S above diagonal may be garbage). Writes f16 P (0 where masked).
__global__ __launch_bounds__(256) void softmax_p(const _Float16* __restrict__ Sc,
                                                 _Float16* __restrict__ Pc) {
  const int l = threadIdx.x & 63;
  const int gid = blockIdx.x * 4 + (threadIdx.x >> 6);
  const int b = gid >> 11, q = gid & 2047;
  const int qt = q >> 8, rq = q & 255;
  const int ntile = qt + 1;
  const size_t base = ((size_t)b * 36 + (size_t)(qt * (qt + 1) / 2)) * 65536 +
                      (size_t)rq * 256 + l * 4;
  float vx[32];
  float m = -__builtin_inff();
#pragma unroll
  for (int c = 0; c < 8; ++c) {
    const int k0 = c * 256 + l * 4;
    float x0 = -__builtin_inff(), x1 = x0, x2 = x0, x3 = x0;
    if (c < ntile) {
      half4 t = *(const half4*)&Sc[base + (size_t)c * 65536];
      x0 = (k0 <= q)     ? (float)t[0] : -__builtin_inff();
      x1 = (k0 + 1 <= q) ? (float)t[1] : -__builtin_inff();
      x2 = (k0 + 2 <= q) ? (float)t[2] : -__builtin_inff();
      x3 = (k0 + 3 <= q) ? (float)t[3] : -__builtin_inff();
    }
    vx[4 * c] = x0; vx[4 * c + 1] = x1; vx[4 * c + 2] = x2; vx[4 * c + 3] = x3;
    m = fmaxf(m, fmaxf(fmaxf(x0, x1), fmaxf(x2, x3)));
  }
#pragma unroll
  for (int s = 1; s < 64; s <<= 1) m = fmaxf(m, __shfl_xor(m, s, 64));
  float sum = 0.f;
#pragma unroll
  for (int i = 0; i < 32; ++i) { vx[i] = __expf(vx[i] - m); sum += vx[i]; }
#pragma unroll
  for (int s = 1; s < 64; s <<= 1) sum += __shfl_xor(sum, s, 64);
  const float inv = 1.f / sum;
  _Float16* Pb = Pc + base;
#pragma unroll
  for (int c = 0; c < 8; ++c) {
    if (c < ntile) {
      half4 p;
      p[0] = (_Float16)(vx[4 * c] * inv);
      p[1] = (_Float16)(vx[4 * c + 1] * inv);
      p[2] = (_Float16)(vx[4 * c + 2] * inv);
      p[3] = (_Float16)(vx[4 * c + 3] * inv);
      *(half4*)&Pb[(size_t)c * 65536] = p;
    }
  }
}

// PV: 1024 jobs, each 128(q) x 128(d); NT=(qt2+1)*2.
// XCD swizzle: j=(bid&7)*128+(bid>>3); b=j>>7 -> one batch per XCD (equal
// work per XCD); within XCD qt2 descends (LPT).
__global__ __launch_bounds__(256, 3) void gemm_pv(const _Float16* __restrict__ Pc,
                                                  const _Float16* __restrict__ VT,
                                                  float* __restrict__ O) {
  __shared__ _Float16 lds[16384];
  const int tid = threadIdx.x;
  const int bid = blockIdx.x;
  const int j = (bid & 7) * 128 + (bid >> 3);  // 1024 = 8*128, bijective
  const int b = j >> 7;                        // one batch per XCD
  const int r = j & 127;
  const int qt2 = 15 - (r >> 3);               // heavy first within XCD
  const int dt = r & 7;
  const int qt = qt2 >> 1;
  const size_t triB = (size_t)b * 36 + (size_t)(qt * (qt + 1) / 2);
  const _Float16* Vb = VT + ((size_t)b * 1024 + dt * 128) * 2048;
  f32x4 acc[4][4] = {};
  auto ga = [&](int t) {
    return Pc + (triB + (t >> 2)) * 65536 + (qt2 & 1) * 32768 + (t & 3) * 64;
  };
  auto gb = [&](int t) { return Vb + t * 64; };
  core128<256, 2048>(ga, gb, (qt2 + 1) * 2, lds, tid, acc);
  const int l = tid & 63, w = tid >> 6;
  const int wm = w >> 1, wn = w & 1;
  const int lr = l & 15, lk = l >> 4;
#pragma unroll
  for (int i = 0; i < 4; ++i) {
#pragma unroll
    for (int jj = 0; jj < 4; ++jj) {
      const int cg = dt * 128 + wn * 64 + jj * 16 + lr;
#pragma unroll
      for (int rr = 0; rr < 4; ++rr) {
        const int rg = qt2 * 128 + wm * 64 + i * 16 + lk * 4 + rr;
        O[((size_t)b * 2048 + rg) * 1024 + cg] = acc[i][jj][rr];
      }
    }
  }
}

extern "C" void kernel_launch(void* const* d_in, const int* in_sizes, int n_in,
                              void* d_out, int out_size, void* d_ws, size_t ws_size,
                              hipStream_t stream) {
  const float* x    = (const float*)d_in[0];
  const float* Wq_w = (const float*)d_in[1];
  const float* Wq_b = (const float*)d_in[2];
  const float* Wk_w = (const float*)d_in[3];
  const float* Wk_b = (const float*)d_in[4];
  const float* Wv_w = (const float*)d_in[5];
  const float* Wv_b = (const float*)d_in[6];
  float* out = (float*)d_out;
  char* ws = (char*)d_ws;
  _Float16* xh  = (_Float16*)(ws);              // 32 MiB (dead after proj)
  _Float16* Wqh = (_Float16*)(ws + 33554432);
  _Float16* Wkh = (_Float16*)(ws + 35651584);
  _Float16* Wvh = (_Float16*)(ws + 37748736);
  _Float16* Sc  = (_Float16*)(ws);              // f16 compact tri S (aliases xh+W)
  _Float16* Qh  = (_Float16*)(ws + 75497472);   // 32 MiB
  _Float16* Kh  = (_Float16*)(ws + 109051904);  // 32 MiB
  _Float16* Pc  = (_Float16*)(ws + 75497472);   // f16 compact tri P (aliases Q/K)
  _Float16* VT  = (_Float16*)(ws + 142606336);  // 32 MiB

  cvt_all<<<2048, 256, 0, stream>>>(x, Wq_w, Wk_w, Wv_w, xh, Wqh, Wkh, Wvh);
  gemm_qkv<<<3072, 256, 0, stream>>>(xh, Wqh, Wkh, Wvh, Wq_b, Wk_b, Wv_b, Qh, Kh, VT);
  gemm_qk<<<1088, 256, 0, stream>>>(Qh, Kh, Sc);
  softmax_p<<<4096, 256, 0, stream>>>(Sc, Pc);
  gemm_pv<<<1024, 256, 0, stream>>>(Pc, VT, out);
}